// Round 14
// baseline (379.232 us; speedup 1.0000x reference)
//
#include <hip/hip_runtime.h>

#define NN 50000
#define EE 500000
#define DD 64
#define GG 50
#define NPG 1000
#define CAP 48   // per-node edge slots (Poisson(10): P(deg>=48) ~ 1e-19)

#define AB2_BLOCKS ((NN + 127) / 128)        // 391 (128-row tiles, 512 thr)
#define SCAT2_BLOCKS ((EE + 511) / 512)      // 977
#define PSTRIDE 392                          // part col stride (AB2_BLOCKS padded)

// ---------------------------------------------------------------- bf16 helpers
__device__ __forceinline__ unsigned short f2bf(float f) {
    unsigned u = __float_as_uint(f);
    u = (u + 0x7fffu + ((u >> 16) & 1u)) >> 16;
    return (unsigned short)u;
}
__device__ __forceinline__ float bf2f(unsigned short s) {
    return __uint_as_float(((unsigned)s) << 16);
}
__device__ __forceinline__ float f4c(const float4& v, int kk) {
    switch (kk) {
        case 0: return v.x;
        case 1: return v.y;
        case 2: return v.z;
        default: return v.w;
    }
}

// ---------------------------------------------------------------- 128x64x64 GEMM pass (512 thr: rg 0..31, cg 0..15)
__device__ __forceinline__ void gemm_pass(const float* sX, const float* sW,
                                          int rg, int c0, float acc[4][4]) {
#pragma unroll 4
    for (int kq = 0; kq < 16; ++kq) {
        float4 x0 = *(const float4*)(&sX[(rg * 4 + 0) * 68 + kq * 4]);
        float4 x1 = *(const float4*)(&sX[(rg * 4 + 1) * 68 + kq * 4]);
        float4 x2 = *(const float4*)(&sX[(rg * 4 + 2) * 68 + kq * 4]);
        float4 x3 = *(const float4*)(&sX[(rg * 4 + 3) * 68 + kq * 4]);
#pragma unroll
        for (int kk = 0; kk < 4; ++kk) {
            float4 w = *(const float4*)(&sW[(kq * 4 + kk) * 64 + c0]);
            float wv[4] = {w.x, w.y, w.z, w.w};
            float a0 = f4c(x0, kk), a1 = f4c(x1, kk), a2 = f4c(x2, kk), a3 = f4c(x3, kk);
#pragma unroll
            for (int cj = 0; cj < 4; ++cj) {
                acc[0][cj] = fmaf(a0, wv[cj], acc[0][cj]);
                acc[1][cj] = fmaf(a1, wv[cj], acc[1][cj]);
                acc[2][cj] = fmaf(a2, wv[cj], acc[2][cj]);
                acc[3][cj] = fmaf(a3, wv[cj], acc[3][cj]);
            }
        }
    }
}

// ---------------------------------------------------------------- layer-0 mega kernel (embed + scatter + ABC)
__global__ __launch_bounds__(512) void k_ab0(const float* __restrict__ hin,
                                             const float* __restrict__ Wemb,
                                             const float* __restrict__ bemb,
                                             const float* __restrict__ Wm,   // 129x64
                                             const float* __restrict__ bm,   // 64
                                             const float* __restrict__ Wu1,  // 64x64
                                             const float* __restrict__ bu,   // 64
                                             const int* __restrict__ src,
                                             const int* __restrict__ dst,
                                             const float* __restrict__ pos,
                                             int* __restrict__ counts,
                                             int2* __restrict__ ep,
                                             unsigned short* __restrict__ A16,
                                             unsigned short* __restrict__ B16,
                                             float* __restrict__ C) {
    __shared__ float sW[64 * 64];    // 16 KB, restaged A->B->C via reg prefetch
    __shared__ float sX[128 * 68];   // 34.8 KB
    __shared__ float sWe[5 * 64];
    __shared__ float sbe[64];
    const int tid = threadIdx.x;

    if (blockIdx.x >= AB2_BLOCKS) {  // ---- scatter branch
        int e = (blockIdx.x - AB2_BLOCKS) * 512 + tid;
        if (e >= EE) return;
        int j = src[e], i = dst[e];
        int c = atomicAdd(&counts[i], 1);
        float dx = pos[2 * i] - pos[2 * j];
        float dy = pos[2 * i + 1] - pos[2 * j + 1];
        ep[(size_t)i * CAP + c] = make_int2(j, __float_as_int(sqrtf(dx * dx + dy * dy)));
        return;
    }

    const int n0 = blockIdx.x * 128;
    for (int i4 = tid; i4 < 64 * 16; i4 += 512)
        ((float4*)sW)[i4] = ((const float4*)Wm)[i4];
    for (int i = tid; i < 320; i += 512) sWe[i] = Wemb[i];
    if (tid < 64) sbe[tid] = bemb[tid];
    __syncthreads();
    // embed straight from global (L1-served)
    for (int i4 = tid; i4 < 128 * 16; i4 += 512) {
        int r = i4 >> 4, kq = i4 & 15;
        int n = n0 + r;
        float4 acc = *(const float4*)(sbe + kq * 4);
        if (n < NN) {
            const float* row = hin + (size_t)n * 5;
#pragma unroll
            for (int q = 0; q < 5; ++q) {
                float hv = row[q];
                float4 wv = *(const float4*)(sWe + q * 64 + kq * 4);
                acc.x = fmaf(hv, wv.x, acc.x);
                acc.y = fmaf(hv, wv.y, acc.y);
                acc.z = fmaf(hv, wv.z, acc.z);
                acc.w = fmaf(hv, wv.w, acc.w);
            }
        }
        acc.x = fmaxf(acc.x, 0.f); acc.y = fmaxf(acc.y, 0.f);
        acc.z = fmaxf(acc.z, 0.f); acc.w = fmaxf(acc.w, 0.f);
        *(float4*)(&sX[r * 68 + kq * 4]) = acc;
    }
    __syncthreads();

    const int rg = tid >> 4;
    const int cg = tid & 15;
    const int c0 = cg * 4;
    float4 pre0, pre1;
    // ---- pass A (bf16 out, R14; prefetch W_B)
    {
        pre0 = ((const float4*)(Wm + 64 * 64))[tid];
        pre1 = ((const float4*)(Wm + 64 * 64))[tid + 512];
        float acc[4][4];
#pragma unroll
        for (int cj = 0; cj < 4; ++cj) {
            float b = bm[c0 + cj];
            acc[0][cj] = b; acc[1][cj] = b; acc[2][cj] = b; acc[3][cj] = b;
        }
        gemm_pass(sX, sW, rg, c0, acc);
#pragma unroll
        for (int ri = 0; ri < 4; ++ri) {
            int n = n0 + rg * 4 + ri;
            if (n >= NN) continue;
            unsigned w0 = (unsigned)f2bf(acc[ri][0]) | ((unsigned)f2bf(acc[ri][1]) << 16);
            unsigned w1 = (unsigned)f2bf(acc[ri][2]) | ((unsigned)f2bf(acc[ri][3]) << 16);
            *(uint2*)(A16 + (size_t)n * DD + c0) = make_uint2(w0, w1);
        }
    }
    __syncthreads();
    ((float4*)sW)[tid] = pre0;
    ((float4*)sW)[tid + 512] = pre1;
    __syncthreads();
    // ---- pass B (bf16 out; prefetch W_C)
    {
        pre0 = ((const float4*)Wu1)[tid];
        pre1 = ((const float4*)Wu1)[tid + 512];
        float acc[4][4];
#pragma unroll
        for (int ri = 0; ri < 4; ++ri)
#pragma unroll
            for (int cj = 0; cj < 4; ++cj) acc[ri][cj] = 0.f;
        gemm_pass(sX, sW, rg, c0, acc);
#pragma unroll
        for (int ri = 0; ri < 4; ++ri) {
            int n = n0 + rg * 4 + ri;
            if (n >= NN) continue;
            unsigned w0 = (unsigned)f2bf(acc[ri][0]) | ((unsigned)f2bf(acc[ri][1]) << 16);
            unsigned w1 = (unsigned)f2bf(acc[ri][2]) | ((unsigned)f2bf(acc[ri][3]) << 16);
            *(uint2*)(B16 + (size_t)n * DD + c0) = make_uint2(w0, w1);
        }
    }
    __syncthreads();
    ((float4*)sW)[tid] = pre0;
    ((float4*)sW)[tid + 512] = pre1;
    __syncthreads();
    // ---- pass C
    {
        float acc[4][4];
#pragma unroll
        for (int cj = 0; cj < 4; ++cj) {
            float b = bu[c0 + cj];
            acc[0][cj] = b; acc[1][cj] = b; acc[2][cj] = b; acc[3][cj] = b;
        }
        gemm_pass(sX, sW, rg, c0, acc);
#pragma unroll
        for (int ri = 0; ri < 4; ++ri) {
            int n = n0 + rg * 4 + ri;
            if (n >= NN) continue;
            *(float4*)(C + (size_t)n * DD + c0) =
                make_float4(acc[ri][0], acc[ri][1], acc[ri][2], acc[ri][3]);
        }
    }
}

// ---------------------------------------------------------------- layer-1 A/B/C GEMM (PairNorm fold; 128-row tiles)
__global__ __launch_bounds__(512) void k_ab1(const float* __restrict__ X,
                                             const float* __restrict__ gmu,
                                             const float* __restrict__ Wm,
                                             const float* __restrict__ bm,
                                             const float* __restrict__ Wu1,
                                             const float* __restrict__ bu,
                                             unsigned short* __restrict__ A16,
                                             unsigned short* __restrict__ B16,
                                             float* __restrict__ C) {
    __shared__ float sW[64 * 64];
    __shared__ float sX[128 * 68];
    const int tid = threadIdx.x;
    const int n0 = blockIdx.x * 128;

    for (int i4 = tid; i4 < 64 * 16; i4 += 512)
        ((float4*)sW)[i4] = ((const float4*)Wm)[i4];
    for (int i4 = tid; i4 < 128 * 16; i4 += 512) {
        int r = i4 >> 4, kq = i4 & 15;
        int n = n0 + r;
        float4 v = make_float4(0.f, 0.f, 0.f, 0.f);
        if (n < NN) v = *(const float4*)(X + (size_t)n * DD + kq * 4);
        float4 mu4 = *(const float4*)(gmu + kq * 4);
        float inv = gmu[64];
        v.x = (v.x - mu4.x) * inv;
        v.y = (v.y - mu4.y) * inv;
        v.z = (v.z - mu4.z) * inv;
        v.w = (v.w - mu4.w) * inv;
        *(float4*)(&sX[r * 68 + kq * 4]) = v;
    }
    __syncthreads();

    const int rg = tid >> 4;
    const int cg = tid & 15;
    const int c0 = cg * 4;
    float4 pre0, pre1;
    {
        pre0 = ((const float4*)(Wm + 64 * 64))[tid];
        pre1 = ((const float4*)(Wm + 64 * 64))[tid + 512];
        float acc[4][4];
#pragma unroll
        for (int cj = 0; cj < 4; ++cj) {
            float b = bm[c0 + cj];
            acc[0][cj] = b; acc[1][cj] = b; acc[2][cj] = b; acc[3][cj] = b;
        }
        gemm_pass(sX, sW, rg, c0, acc);
#pragma unroll
        for (int ri = 0; ri < 4; ++ri) {
            int n = n0 + rg * 4 + ri;
            if (n >= NN) continue;
            unsigned w0 = (unsigned)f2bf(acc[ri][0]) | ((unsigned)f2bf(acc[ri][1]) << 16);
            unsigned w1 = (unsigned)f2bf(acc[ri][2]) | ((unsigned)f2bf(acc[ri][3]) << 16);
            *(uint2*)(A16 + (size_t)n * DD + c0) = make_uint2(w0, w1);
        }
    }
    __syncthreads();
    ((float4*)sW)[tid] = pre0;
    ((float4*)sW)[tid + 512] = pre1;
    __syncthreads();
    {
        pre0 = ((const float4*)Wu1)[tid];
        pre1 = ((const float4*)Wu1)[tid + 512];
        float acc[4][4];
#pragma unroll
        for (int ri = 0; ri < 4; ++ri)
#pragma unroll
            for (int cj = 0; cj < 4; ++cj) acc[ri][cj] = 0.f;
        gemm_pass(sX, sW, rg, c0, acc);
#pragma unroll
        for (int ri = 0; ri < 4; ++ri) {
            int n = n0 + rg * 4 + ri;
            if (n >= NN) continue;
            unsigned w0 = (unsigned)f2bf(acc[ri][0]) | ((unsigned)f2bf(acc[ri][1]) << 16);
            unsigned w1 = (unsigned)f2bf(acc[ri][2]) | ((unsigned)f2bf(acc[ri][3]) << 16);
            *(uint2*)(B16 + (size_t)n * DD + c0) = make_uint2(w0, w1);
        }
    }
    __syncthreads();
    ((float4*)sW)[tid] = pre0;
    ((float4*)sW)[tid + 512] = pre1;
    __syncthreads();
    {
        float acc[4][4];
#pragma unroll
        for (int cj = 0; cj < 4; ++cj) {
            float b = bu[c0 + cj];
            acc[0][cj] = b; acc[1][cj] = b; acc[2][cj] = b; acc[3][cj] = b;
        }
        gemm_pass(sX, sW, rg, c0, acc);
#pragma unroll
        for (int ri = 0; ri < 4; ++ri) {
            int n = n0 + rg * 4 + ri;
            if (n >= NN) continue;
            *(float4*)(C + (size_t)n * DD + c0) =
                make_float4(acc[ri][0], acc[ri][1], acc[ri][2], acc[ri][3]);
        }
    }
}

// ---------------------------------------------------------------- gather (lane-per-slot; A now bf16)
__global__ __launch_bounds__(256) void k_edge(const unsigned short* __restrict__ A16,
                                              const unsigned short* __restrict__ B16,
                                              const float* __restrict__ w128,
                                              const int* __restrict__ counts,
                                              const int2* __restrict__ ep,
                                              float* __restrict__ aggr) {
    int i = (blockIdx.x * 256 + threadIdx.x) >> 6;
    int lane = threadIdx.x & 63;
    if (i >= NN) return;
    int2 e = make_int2(0, 0);
    if (lane < CAP) e = ep[(size_t)i * CAP + lane];   // whole edge list, one 384B load
    float w = w128[lane];
    float a = bf2f(A16[(size_t)i * DD + lane]);
    int cnt = counts[i];
    float acc0 = 0.f, acc1 = 0.f, acc2 = 0.f, acc3 = 0.f;
    for (int q0 = 0; q0 < cnt; q0 += 16) {
        int jj[16]; float dd[16];
#pragma unroll
        for (int qq = 0; qq < 16; ++qq) {
            jj[qq] = __shfl(e.x, q0 + qq);
            dd[qq] = __int_as_float(__shfl(e.y, q0 + qq));
        }
        float v[16];
#pragma unroll
        for (int qq = 0; qq < 16; ++qq) {
            unsigned ju = min((unsigned)jj[qq], (unsigned)(NN - 1));
            v[qq] = bf2f(B16[(size_t)ju * DD + lane]);
        }
#pragma unroll
        for (int qq = 0; qq < 16; ++qq) {
            float m = fmaxf(fmaf(dd[qq], w, a) + v[qq], 0.f);
            float mm = (q0 + qq < cnt) ? m : 0.f;
            switch (qq & 3) {
                case 0: acc0 += mm; break;
                case 1: acc1 += mm; break;
                case 2: acc2 += mm; break;
                default: acc3 += mm; break;
            }
        }
    }
    aggr[(size_t)i * DD + lane] = (acc0 + acc1) + (acc2 + acc3);
}

// ---------------------------------------------------------------- update GEMM + fused PairNorm stats (ticket/last-block, R14)
// Blocks write TRANSPOSED partials part[col*PSTRIDE + blockIdx] (finalizer reads
// contiguously -- R8 lesson); fence+ticket; last block reduces 65x391 and writes gmu.
__global__ __launch_bounds__(512) void k_upd(const float* __restrict__ ag,
                                             const float* __restrict__ C,
                                             const float* __restrict__ Wu2,
                                             float* __restrict__ hraw,
                                             float* __restrict__ part,
                                             float* __restrict__ gmu,
                                             int* __restrict__ counter) {
    __shared__ float sW[64 * 64];
    __shared__ float sX[128 * 68];
    __shared__ float sQw[8];
    __shared__ int sticket;
    __shared__ float sQs;
    const int tid = threadIdx.x;
    const int n0 = blockIdx.x * 128;
    const int rg = tid >> 4;
    const int cg = tid & 15;
    const int c0 = cg * 4;

    for (int i4 = tid; i4 < 64 * 16; i4 += 512)
        ((float4*)sW)[i4] = ((const float4*)Wu2)[i4];
    for (int i4 = tid; i4 < 128 * 16; i4 += 512) {
        int r = i4 >> 4, kq = i4 & 15;
        int n = n0 + r;
        float4 v = make_float4(0.f, 0.f, 0.f, 0.f);
        if (n < NN) v = *(const float4*)(ag + (size_t)n * DD + kq * 4);
        *(float4*)(&sX[r * 68 + kq * 4]) = v;
    }
    __syncthreads();

    float acc[4][4];
#pragma unroll
    for (int ri = 0; ri < 4; ++ri)
#pragma unroll
        for (int cj = 0; cj < 4; ++cj) acc[ri][cj] = 0.f;
    gemm_pass(sX, sW, rg, c0, acc);

    float lsq = 0.f;
    float4 csum = make_float4(0.f, 0.f, 0.f, 0.f);
#pragma unroll
    for (int ri = 0; ri < 4; ++ri) {
        int n = n0 + rg * 4 + ri;
        if (n >= NN) continue;
        float4 cv = *(const float4*)(C + (size_t)n * DD + c0);
        float r0 = fmaxf(acc[ri][0] + cv.x, 0.f);
        float r1 = fmaxf(acc[ri][1] + cv.y, 0.f);
        float r2 = fmaxf(acc[ri][2] + cv.z, 0.f);
        float r3 = fmaxf(acc[ri][3] + cv.w, 0.f);
        *(float4*)(hraw + (size_t)n * DD + c0) = make_float4(r0, r1, r2, r3);
        lsq += r0 * r0 + r1 * r1 + r2 * r2 + r3 * r3;
        csum.x += r0; csum.y += r1; csum.z += r2; csum.w += r3;
    }
    __syncthreads();
    *(float4*)(&sX[rg * 68 + c0]) = csum;   // rows 0..31 scratch
#pragma unroll
    for (int off = 32; off > 0; off >>= 1) lsq += __shfl_down(lsq, off);
    if ((tid & 63) == 0) sQw[tid >> 6] = lsq;
    __syncthreads();
    if (tid < 64) {
        float s = 0.f;
#pragma unroll
        for (int rr = 0; rr < 32; ++rr) s += sX[rr * 68 + tid];
        part[(size_t)tid * PSTRIDE + blockIdx.x] = s;
    } else if (tid == 64) {
        float Q = 0.f;
#pragma unroll
        for (int w = 0; w < 8; ++w) Q += sQw[w];
        part[(size_t)64 * PSTRIDE + blockIdx.x] = Q;
    }
    __threadfence();   // release: part writes visible before ticket
    __syncthreads();
    if (tid == 0) sticket = atomicAdd(counter, 1);
    __syncthreads();
    if (sticket != AB2_BLOCKS - 1) return;
    __threadfence();   // acquire side

    // ---- finalize: reduce 65 cols x 391 blocks (contiguous per column)
    float* sred = sX;  // reuse scratch (all prior readers done)
    if (tid < 455) {
        int col = tid / 7, chunk = tid % 7;
        int r0 = chunk * 56;
        int r1 = min(r0 + 56, AB2_BLOCKS);
        float s = 0.f;
        for (int r = r0; r < r1; ++r) s += part[(size_t)col * PSTRIDE + r];
        sred[col * 8 + chunk] = s;
    }
    __syncthreads();
    float tot = 0.f;
    if (tid < 65) {
#pragma unroll
        for (int ch = 0; ch < 7; ++ch) tot += sred[tid * 8 + ch];
        if (tid == 64) sQs = tot;
    }
    __syncthreads();
    if (tid < 64) {
        float mu = tot * (1.f / NN);
        gmu[tid] = mu;
        float v = mu * mu;
#pragma unroll
        for (int off = 32; off > 0; off >>= 1) v += __shfl_down(v, off);
        if (tid == 0) {
            gmu[64] = 1.f / sqrtf(1e-5f + sQs * (1.f / NN) - v);
            *counter = 0;  // ready for next invocation (stream-ordered)
        }
    }
}

// ---------------------------------------------------------------- pool + head (max commutes w/ positive affine)
__global__ __launch_bounds__(1024) void k_poolhead(const float* __restrict__ h,
                                                   const float* __restrict__ gmu,
                                                   const float* __restrict__ W1,
                                                   const float* __restrict__ b1,
                                                   const float* __restrict__ W2,
                                                   const float* __restrict__ b2,
                                                   float* __restrict__ out) {
    __shared__ float sm[16][DD];
    __shared__ float shg[DD];
    __shared__ float st[DD];
    int g = blockIdx.x;
    int t = threadIdx.x, d = t & 63, c = t >> 6;
    const int per = (NPG + 15) / 16;  // 63
    int n0 = g * NPG + c * per;
    int n1 = g * NPG + NPG;
    if (n0 + per < n1) n1 = n0 + per;
    float m = -3.0e38f;
    for (int n = n0; n < n1; ++n) m = fmaxf(m, h[(size_t)n * DD + d]);
    sm[c][d] = m;
    __syncthreads();
    if (c == 0) {
#pragma unroll
        for (int cc = 1; cc < 16; ++cc) m = fmaxf(m, sm[cc][d]);
        shg[d] = (m - gmu[d]) * gmu[64];
    }
    __syncthreads();
    if (t < DD) {
        float acc = b1[t];
        for (int k = 0; k < DD; ++k) acc = fmaf(shg[k], W1[k * DD + t], acc);
        st[t] = fmaxf(acc, 0.f);
    }
    __syncthreads();
    if (t < 2) {
        float o = b2[t];
        for (int k = 0; k < DD; ++k) o = fmaf(st[k], W2[k * 2 + t], o);
        out[g * 2 + t] = o;
    }
}

// ---------------------------------------------------------------- launch
extern "C" void kernel_launch(void* const* d_in, const int* in_sizes, int n_in,
                              void* d_out, int out_size, void* d_ws, size_t ws_size,
                              hipStream_t stream) {
    (void)in_sizes; (void)n_in; (void)out_size; (void)ws_size;
    const float* h_in = (const float*)d_in[0];
    const float* pos  = (const float*)d_in[1];
    const int*   eidx = (const int*)d_in[2];
    const float* Wemb = (const float*)d_in[4];
    const float* bemb = (const float*)d_in[5];
    const float* msgW = (const float*)d_in[6]; // 2 x 129 x 64
    const float* msgb = (const float*)d_in[7]; // 2 x 64
    const float* updW = (const float*)d_in[8]; // 2 x 128 x 64
    const float* updb = (const float*)d_in[9]; // 2 x 64
    const float* W1   = (const float*)d_in[10];
    const float* b1   = (const float*)d_in[11];
    const float* W2   = (const float*)d_in[12];
    const float* b2   = (const float*)d_in[13];
    float* out = (float*)d_out;

    float* hbuf  = (float*)d_ws;                 // N*64 fp32 (layer-1 C / final hraw)
    float* Cbuf  = hbuf + NN * DD;               // N*64 fp32 (layer-0 C / hraw0)
    float* aggr  = Cbuf + NN * DD;               // N*64 fp32
    unsigned short* A16 = (unsigned short*)(aggr + NN * DD);  // N*64 bf16
    unsigned short* B16 = A16 + NN * DD;         // N*64 bf16
    float* gmu0  = (float*)(B16 + NN * DD);      // 66
    float* gmu1  = gmu0 + 66;                    // 66
    float* part  = gmu1 + 66;                    // 65*PSTRIDE
    int* counts  = (int*)(part + 65 * PSTRIDE);  // N (zeroed)
    int* counter = counts + NN;                  // 1 (zeroed)
    int2* ep     = (int2*)(counts + NN + 4);     // N*CAP slots

    const int* src = eidx;
    const int* dst = eidx + EE;

    hipMemsetAsync(counts, 0, (NN + 4) * sizeof(int), stream);

    // ---- layer 0 (embed + scatter + ABC in one dispatch)
    k_ab0<<<AB2_BLOCKS + SCAT2_BLOCKS, 512, 0, stream>>>(
        h_in, Wemb, bemb, msgW, msgb, updW, updb,
        src, dst, pos, counts, ep, A16, B16, Cbuf);
    k_edge<<<(NN + 3) / 4, 256, 0, stream>>>(A16, B16, msgW + 128 * DD,
                                             counts, ep, aggr);
    k_upd<<<AB2_BLOCKS, 512, 0, stream>>>(aggr, Cbuf, updW + 64 * DD, Cbuf,
                                          part, gmu0, counter);

    // ---- layer 1
    {
        const float* Wm = msgW + 129 * DD;
        k_ab1<<<AB2_BLOCKS, 512, 0, stream>>>(Cbuf, gmu0, Wm, msgb + DD,
                                              updW + 128 * DD, updb + DD,
                                              A16, B16, hbuf);
        k_edge<<<(NN + 3) / 4, 256, 0, stream>>>(A16, B16, Wm + 128 * DD,
                                                 counts, ep, aggr);
        k_upd<<<AB2_BLOCKS, 512, 0, stream>>>(aggr, hbuf, updW + 192 * DD, hbuf,
                                              part, gmu1, counter);
    }

    k_poolhead<<<GG, 1024, 0, stream>>>(hbuf, gmu1, W1, b1, W2, b2, out);
}

// Round 15
// 237.435 us; speedup vs baseline: 1.5972x; 1.5972x over previous
//
#include <hip/hip_runtime.h>

#define NN 50000
#define EE 500000
#define DD 64
#define GG 50
#define NPG 1000
#define CAP 48   // per-node edge slots (Poisson(10): P(deg>=48) ~ 1e-19)

#define AB2_BLOCKS ((NN + 127) / 128)        // 391 (128-row tiles, 512 thr)
#define SCAT2_BLOCKS ((EE + 511) / 512)      // 977
#define S1_BLOCKS 64

// ---------------------------------------------------------------- bf16 helpers
__device__ __forceinline__ unsigned short f2bf(float f) {
    unsigned u = __float_as_uint(f);
    u = (u + 0x7fffu + ((u >> 16) & 1u)) >> 16;
    return (unsigned short)u;
}
__device__ __forceinline__ float bf2f(unsigned short s) {
    return __uint_as_float(((unsigned)s) << 16);
}
__device__ __forceinline__ float f4c(const float4& v, int kk) {
    switch (kk) {
        case 0: return v.x;
        case 1: return v.y;
        case 2: return v.z;
        default: return v.w;
    }
}

// ---------------------------------------------------------------- 128x64x64 GEMM pass (512 thr: rg 0..31, cg 0..15)
__device__ __forceinline__ void gemm_pass(const float* sX, const float* sW,
                                          int rg, int c0, float acc[4][4]) {
#pragma unroll 4
    for (int kq = 0; kq < 16; ++kq) {
        float4 x0 = *(const float4*)(&sX[(rg * 4 + 0) * 68 + kq * 4]);
        float4 x1 = *(const float4*)(&sX[(rg * 4 + 1) * 68 + kq * 4]);
        float4 x2 = *(const float4*)(&sX[(rg * 4 + 2) * 68 + kq * 4]);
        float4 x3 = *(const float4*)(&sX[(rg * 4 + 3) * 68 + kq * 4]);
#pragma unroll
        for (int kk = 0; kk < 4; ++kk) {
            float4 w = *(const float4*)(&sW[(kq * 4 + kk) * 64 + c0]);
            float wv[4] = {w.x, w.y, w.z, w.w};
            float a0 = f4c(x0, kk), a1 = f4c(x1, kk), a2 = f4c(x2, kk), a3 = f4c(x3, kk);
#pragma unroll
            for (int cj = 0; cj < 4; ++cj) {
                acc[0][cj] = fmaf(a0, wv[cj], acc[0][cj]);
                acc[1][cj] = fmaf(a1, wv[cj], acc[1][cj]);
                acc[2][cj] = fmaf(a2, wv[cj], acc[2][cj]);
                acc[3][cj] = fmaf(a3, wv[cj], acc[3][cj]);
            }
        }
    }
}

// ---------------------------------------------------------------- layer-0 mega kernel (embed + scatter + ABC)
__global__ __launch_bounds__(512) void k_ab0(const float* __restrict__ hin,
                                             const float* __restrict__ Wemb,
                                             const float* __restrict__ bemb,
                                             const float* __restrict__ Wm,   // 129x64
                                             const float* __restrict__ bm,   // 64
                                             const float* __restrict__ Wu1,  // 64x64
                                             const float* __restrict__ bu,   // 64
                                             const int* __restrict__ src,
                                             const int* __restrict__ dst,
                                             const float* __restrict__ pos,
                                             int* __restrict__ counts,
                                             int2* __restrict__ ep,
                                             unsigned short* __restrict__ A16,
                                             unsigned short* __restrict__ B16,
                                             float* __restrict__ C) {
    __shared__ float sW[64 * 64];    // 16 KB, restaged A->B->C via reg prefetch
    __shared__ float sX[128 * 68];   // 34.8 KB
    __shared__ float sWe[5 * 64];
    __shared__ float sbe[64];
    const int tid = threadIdx.x;

    if (blockIdx.x >= AB2_BLOCKS) {  // ---- scatter branch
        int e = (blockIdx.x - AB2_BLOCKS) * 512 + tid;
        if (e >= EE) return;
        int j = src[e], i = dst[e];
        int c = atomicAdd(&counts[i], 1);
        float dx = pos[2 * i] - pos[2 * j];
        float dy = pos[2 * i + 1] - pos[2 * j + 1];
        ep[(size_t)i * CAP + c] = make_int2(j, __float_as_int(sqrtf(dx * dx + dy * dy)));
        return;
    }

    const int n0 = blockIdx.x * 128;
    for (int i4 = tid; i4 < 64 * 16; i4 += 512)
        ((float4*)sW)[i4] = ((const float4*)Wm)[i4];
    for (int i = tid; i < 320; i += 512) sWe[i] = Wemb[i];
    if (tid < 64) sbe[tid] = bemb[tid];
    __syncthreads();
    // embed straight from global (L1-served)
    for (int i4 = tid; i4 < 128 * 16; i4 += 512) {
        int r = i4 >> 4, kq = i4 & 15;
        int n = n0 + r;
        float4 acc = *(const float4*)(sbe + kq * 4);
        if (n < NN) {
            const float* row = hin + (size_t)n * 5;
#pragma unroll
            for (int q = 0; q < 5; ++q) {
                float hv = row[q];
                float4 wv = *(const float4*)(sWe + q * 64 + kq * 4);
                acc.x = fmaf(hv, wv.x, acc.x);
                acc.y = fmaf(hv, wv.y, acc.y);
                acc.z = fmaf(hv, wv.z, acc.z);
                acc.w = fmaf(hv, wv.w, acc.w);
            }
        }
        acc.x = fmaxf(acc.x, 0.f); acc.y = fmaxf(acc.y, 0.f);
        acc.z = fmaxf(acc.z, 0.f); acc.w = fmaxf(acc.w, 0.f);
        *(float4*)(&sX[r * 68 + kq * 4]) = acc;
    }
    __syncthreads();

    const int rg = tid >> 4;
    const int cg = tid & 15;
    const int c0 = cg * 4;
    float4 pre0, pre1;
    // ---- pass A (bf16 out; prefetch W_B)
    {
        pre0 = ((const float4*)(Wm + 64 * 64))[tid];
        pre1 = ((const float4*)(Wm + 64 * 64))[tid + 512];
        float acc[4][4];
#pragma unroll
        for (int cj = 0; cj < 4; ++cj) {
            float b = bm[c0 + cj];
            acc[0][cj] = b; acc[1][cj] = b; acc[2][cj] = b; acc[3][cj] = b;
        }
        gemm_pass(sX, sW, rg, c0, acc);
#pragma unroll
        for (int ri = 0; ri < 4; ++ri) {
            int n = n0 + rg * 4 + ri;
            if (n >= NN) continue;
            unsigned w0 = (unsigned)f2bf(acc[ri][0]) | ((unsigned)f2bf(acc[ri][1]) << 16);
            unsigned w1 = (unsigned)f2bf(acc[ri][2]) | ((unsigned)f2bf(acc[ri][3]) << 16);
            *(uint2*)(A16 + (size_t)n * DD + c0) = make_uint2(w0, w1);
        }
    }
    __syncthreads();
    ((float4*)sW)[tid] = pre0;
    ((float4*)sW)[tid + 512] = pre1;
    __syncthreads();
    // ---- pass B (bf16 out; prefetch W_C)
    {
        pre0 = ((const float4*)Wu1)[tid];
        pre1 = ((const float4*)Wu1)[tid + 512];
        float acc[4][4];
#pragma unroll
        for (int ri = 0; ri < 4; ++ri)
#pragma unroll
            for (int cj = 0; cj < 4; ++cj) acc[ri][cj] = 0.f;
        gemm_pass(sX, sW, rg, c0, acc);
#pragma unroll
        for (int ri = 0; ri < 4; ++ri) {
            int n = n0 + rg * 4 + ri;
            if (n >= NN) continue;
            unsigned w0 = (unsigned)f2bf(acc[ri][0]) | ((unsigned)f2bf(acc[ri][1]) << 16);
            unsigned w1 = (unsigned)f2bf(acc[ri][2]) | ((unsigned)f2bf(acc[ri][3]) << 16);
            *(uint2*)(B16 + (size_t)n * DD + c0) = make_uint2(w0, w1);
        }
    }
    __syncthreads();
    ((float4*)sW)[tid] = pre0;
    ((float4*)sW)[tid + 512] = pre1;
    __syncthreads();
    // ---- pass C
    {
        float acc[4][4];
#pragma unroll
        for (int cj = 0; cj < 4; ++cj) {
            float b = bu[c0 + cj];
            acc[0][cj] = b; acc[1][cj] = b; acc[2][cj] = b; acc[3][cj] = b;
        }
        gemm_pass(sX, sW, rg, c0, acc);
#pragma unroll
        for (int ri = 0; ri < 4; ++ri) {
            int n = n0 + rg * 4 + ri;
            if (n >= NN) continue;
            *(float4*)(C + (size_t)n * DD + c0) =
                make_float4(acc[ri][0], acc[ri][1], acc[ri][2], acc[ri][3]);
        }
    }
}

// ---------------------------------------------------------------- layer-1 A/B/C GEMM (PairNorm fold; 128-row tiles)
__global__ __launch_bounds__(512) void k_ab1(const float* __restrict__ X,
                                             const float* __restrict__ gmu,
                                             const float* __restrict__ Wm,
                                             const float* __restrict__ bm,
                                             const float* __restrict__ Wu1,
                                             const float* __restrict__ bu,
                                             unsigned short* __restrict__ A16,
                                             unsigned short* __restrict__ B16,
                                             float* __restrict__ C) {
    __shared__ float sW[64 * 64];
    __shared__ float sX[128 * 68];
    const int tid = threadIdx.x;
    const int n0 = blockIdx.x * 128;

    for (int i4 = tid; i4 < 64 * 16; i4 += 512)
        ((float4*)sW)[i4] = ((const float4*)Wm)[i4];
    for (int i4 = tid; i4 < 128 * 16; i4 += 512) {
        int r = i4 >> 4, kq = i4 & 15;
        int n = n0 + r;
        float4 v = make_float4(0.f, 0.f, 0.f, 0.f);
        if (n < NN) v = *(const float4*)(X + (size_t)n * DD + kq * 4);
        float4 mu4 = *(const float4*)(gmu + kq * 4);
        float inv = gmu[64];
        v.x = (v.x - mu4.x) * inv;
        v.y = (v.y - mu4.y) * inv;
        v.z = (v.z - mu4.z) * inv;
        v.w = (v.w - mu4.w) * inv;
        *(float4*)(&sX[r * 68 + kq * 4]) = v;
    }
    __syncthreads();

    const int rg = tid >> 4;
    const int cg = tid & 15;
    const int c0 = cg * 4;
    float4 pre0, pre1;
    {
        pre0 = ((const float4*)(Wm + 64 * 64))[tid];
        pre1 = ((const float4*)(Wm + 64 * 64))[tid + 512];
        float acc[4][4];
#pragma unroll
        for (int cj = 0; cj < 4; ++cj) {
            float b = bm[c0 + cj];
            acc[0][cj] = b; acc[1][cj] = b; acc[2][cj] = b; acc[3][cj] = b;
        }
        gemm_pass(sX, sW, rg, c0, acc);
#pragma unroll
        for (int ri = 0; ri < 4; ++ri) {
            int n = n0 + rg * 4 + ri;
            if (n >= NN) continue;
            unsigned w0 = (unsigned)f2bf(acc[ri][0]) | ((unsigned)f2bf(acc[ri][1]) << 16);
            unsigned w1 = (unsigned)f2bf(acc[ri][2]) | ((unsigned)f2bf(acc[ri][3]) << 16);
            *(uint2*)(A16 + (size_t)n * DD + c0) = make_uint2(w0, w1);
        }
    }
    __syncthreads();
    ((float4*)sW)[tid] = pre0;
    ((float4*)sW)[tid + 512] = pre1;
    __syncthreads();
    {
        pre0 = ((const float4*)Wu1)[tid];
        pre1 = ((const float4*)Wu1)[tid + 512];
        float acc[4][4];
#pragma unroll
        for (int ri = 0; ri < 4; ++ri)
#pragma unroll
            for (int cj = 0; cj < 4; ++cj) acc[ri][cj] = 0.f;
        gemm_pass(sX, sW, rg, c0, acc);
#pragma unroll
        for (int ri = 0; ri < 4; ++ri) {
            int n = n0 + rg * 4 + ri;
            if (n >= NN) continue;
            unsigned w0 = (unsigned)f2bf(acc[ri][0]) | ((unsigned)f2bf(acc[ri][1]) << 16);
            unsigned w1 = (unsigned)f2bf(acc[ri][2]) | ((unsigned)f2bf(acc[ri][3]) << 16);
            *(uint2*)(B16 + (size_t)n * DD + c0) = make_uint2(w0, w1);
        }
    }
    __syncthreads();
    ((float4*)sW)[tid] = pre0;
    ((float4*)sW)[tid + 512] = pre1;
    __syncthreads();
    {
        float acc[4][4];
#pragma unroll
        for (int cj = 0; cj < 4; ++cj) {
            float b = bu[c0 + cj];
            acc[0][cj] = b; acc[1][cj] = b; acc[2][cj] = b; acc[3][cj] = b;
        }
        gemm_pass(sX, sW, rg, c0, acc);
#pragma unroll
        for (int ri = 0; ri < 4; ++ri) {
            int n = n0 + rg * 4 + ri;
            if (n >= NN) continue;
            *(float4*)(C + (size_t)n * DD + c0) =
                make_float4(acc[ri][0], acc[ri][1], acc[ri][2], acc[ri][3]);
        }
    }
}

// ---------------------------------------------------------------- gather (lane-per-slot; A bf16)
__global__ __launch_bounds__(256) void k_edge(const unsigned short* __restrict__ A16,
                                              const unsigned short* __restrict__ B16,
                                              const float* __restrict__ w128,
                                              const int* __restrict__ counts,
                                              const int2* __restrict__ ep,
                                              float* __restrict__ aggr) {
    int i = (blockIdx.x * 256 + threadIdx.x) >> 6;
    int lane = threadIdx.x & 63;
    if (i >= NN) return;
    int2 e = make_int2(0, 0);
    if (lane < CAP) e = ep[(size_t)i * CAP + lane];   // whole edge list, one 384B load
    float w = w128[lane];
    float a = bf2f(A16[(size_t)i * DD + lane]);
    int cnt = counts[i];
    float acc0 = 0.f, acc1 = 0.f, acc2 = 0.f, acc3 = 0.f;
    for (int q0 = 0; q0 < cnt; q0 += 16) {
        int jj[16]; float dd[16];
#pragma unroll
        for (int qq = 0; qq < 16; ++qq) {
            jj[qq] = __shfl(e.x, q0 + qq);
            dd[qq] = __int_as_float(__shfl(e.y, q0 + qq));
        }
        float v[16];
#pragma unroll
        for (int qq = 0; qq < 16; ++qq) {
            unsigned ju = min((unsigned)jj[qq], (unsigned)(NN - 1));
            v[qq] = bf2f(B16[(size_t)ju * DD + lane]);
        }
#pragma unroll
        for (int qq = 0; qq < 16; ++qq) {
            float m = fmaxf(fmaf(dd[qq], w, a) + v[qq], 0.f);
            float mm = (q0 + qq < cnt) ? m : 0.f;
            switch (qq & 3) {
                case 0: acc0 += mm; break;
                case 1: acc1 += mm; break;
                case 2: acc2 += mm; break;
                default: acc3 += mm; break;
            }
        }
    }
    aggr[(size_t)i * DD + lane] = (acc0 + acc1) + (acc2 + acc3);
}

// ---------------------------------------------------------------- update GEMM + per-block stats partials (R13 structure)
// R15 REVERT: no fence/ticket here — R14's per-block __threadfence had to drain
// 32 KB of dirty hraw per block to device scope before the ticket (391 blocks
// => L2-writeback storm, 92 us). Partials row-major; tiny k_stats owns the fence.
__global__ __launch_bounds__(512) void k_upd(const float* __restrict__ ag,
                                             const float* __restrict__ C,
                                             const float* __restrict__ Wu2,
                                             float* __restrict__ hraw,
                                             float* __restrict__ part) {
    __shared__ float sW[64 * 64];
    __shared__ float sX[128 * 68];
    __shared__ float sQw[8];
    const int tid = threadIdx.x;
    const int n0 = blockIdx.x * 128;
    const int rg = tid >> 4;
    const int cg = tid & 15;
    const int c0 = cg * 4;

    for (int i4 = tid; i4 < 64 * 16; i4 += 512)
        ((float4*)sW)[i4] = ((const float4*)Wu2)[i4];
    for (int i4 = tid; i4 < 128 * 16; i4 += 512) {
        int r = i4 >> 4, kq = i4 & 15;
        int n = n0 + r;
        float4 v = make_float4(0.f, 0.f, 0.f, 0.f);
        if (n < NN) v = *(const float4*)(ag + (size_t)n * DD + kq * 4);
        *(float4*)(&sX[r * 68 + kq * 4]) = v;
    }
    __syncthreads();

    float acc[4][4];
#pragma unroll
    for (int ri = 0; ri < 4; ++ri)
#pragma unroll
        for (int cj = 0; cj < 4; ++cj) acc[ri][cj] = 0.f;
    gemm_pass(sX, sW, rg, c0, acc);

    float lsq = 0.f;
    float4 csum = make_float4(0.f, 0.f, 0.f, 0.f);
#pragma unroll
    for (int ri = 0; ri < 4; ++ri) {
        int n = n0 + rg * 4 + ri;
        if (n >= NN) continue;
        float4 cv = *(const float4*)(C + (size_t)n * DD + c0);
        float r0 = fmaxf(acc[ri][0] + cv.x, 0.f);
        float r1 = fmaxf(acc[ri][1] + cv.y, 0.f);
        float r2 = fmaxf(acc[ri][2] + cv.z, 0.f);
        float r3 = fmaxf(acc[ri][3] + cv.w, 0.f);
        *(float4*)(hraw + (size_t)n * DD + c0) = make_float4(r0, r1, r2, r3);
        lsq += r0 * r0 + r1 * r1 + r2 * r2 + r3 * r3;
        csum.x += r0; csum.y += r1; csum.z += r2; csum.w += r3;
    }
    __syncthreads();
    *(float4*)(&sX[rg * 68 + c0]) = csum;   // rows 0..31 scratch
#pragma unroll
    for (int off = 32; off > 0; off >>= 1) lsq += __shfl_down(lsq, off);
    if ((tid & 63) == 0) sQw[tid >> 6] = lsq;
    __syncthreads();
    if (tid < 64) {
        float s = 0.f;
#pragma unroll
        for (int rr = 0; rr < 32; ++rr) s += sX[rr * 68 + tid];
        part[(size_t)blockIdx.x * 68 + tid] = s;
    } else if (tid == 64) {
        float Q = 0.f;
#pragma unroll
        for (int w = 0; w < 8; ++w) Q += sQw[w];
        part[(size_t)blockIdx.x * 68 + 64] = Q;
    } else if (tid < 68) {
        part[(size_t)blockIdx.x * 68 + tid] = 0.f;  // unused q slots zero
    }
}

// ---------------------------------------------------------------- stats: stripe-reduce + last-block finalize (64 blocks, tiny dirty set)
__global__ __launch_bounds__(128) void k_stats(const float* __restrict__ part,
                                               float* __restrict__ part2,
                                               float* __restrict__ gmu,
                                               int* __restrict__ counter) {
    __shared__ int sticket;
    __shared__ float sq4[4];
    int t = threadIdx.x;
    if (t < 68) {
        float s0 = 0.f, s1 = 0.f, s2 = 0.f, s3 = 0.f;
        int b = blockIdx.x;
        for (; b + 3 * S1_BLOCKS < AB2_BLOCKS; b += 4 * S1_BLOCKS) {
            s0 += part[(size_t)b * 68 + t];
            s1 += part[(size_t)(b + S1_BLOCKS) * 68 + t];
            s2 += part[(size_t)(b + 2 * S1_BLOCKS) * 68 + t];
            s3 += part[(size_t)(b + 3 * S1_BLOCKS) * 68 + t];
        }
        for (; b < AB2_BLOCKS; b += S1_BLOCKS) s0 += part[(size_t)b * 68 + t];
        part2[blockIdx.x * 68 + t] = (s0 + s1) + (s2 + s3);
    }
    __threadfence();
    __syncthreads();
    if (t == 0) sticket = atomicAdd(counter, 1);
    __syncthreads();
    if (sticket != S1_BLOCKS - 1) return;
    __threadfence();
    float s = 0.f;
    if (t < 68) {
        for (int b = 0; b < S1_BLOCKS; ++b) s += part2[b * 68 + t];
    }
    if (t >= 64 && t < 68) sq4[t - 64] = s;
    __syncthreads();
    if (t < 64) {
        float mu = s * (1.f / NN);
        gmu[t] = mu;
        float v = mu * mu;
#pragma unroll
        for (int off = 32; off > 0; off >>= 1) v += __shfl_down(v, off);
        if (t == 0) {
            float Q = sq4[0] + sq4[1] + sq4[2] + sq4[3];
            gmu[64] = 1.f / sqrtf(1e-5f + Q * (1.f / NN) - v);
            *counter = 0;
        }
    }
}

// ---------------------------------------------------------------- pool + head (max commutes w/ positive affine)
__global__ __launch_bounds__(1024) void k_poolhead(const float* __restrict__ h,
                                                   const float* __restrict__ gmu,
                                                   const float* __restrict__ W1,
                                                   const float* __restrict__ b1,
                                                   const float* __restrict__ W2,
                                                   const float* __restrict__ b2,
                                                   float* __restrict__ out) {
    __shared__ float sm[16][DD];
    __shared__ float shg[DD];
    __shared__ float st[DD];
    int g = blockIdx.x;
    int t = threadIdx.x, d = t & 63, c = t >> 6;
    const int per = (NPG + 15) / 16;  // 63
    int n0 = g * NPG + c * per;
    int n1 = g * NPG + NPG;
    if (n0 + per < n1) n1 = n0 + per;
    float m = -3.0e38f;
    for (int n = n0; n < n1; ++n) m = fmaxf(m, h[(size_t)n * DD + d]);
    sm[c][d] = m;
    __syncthreads();
    if (c == 0) {
#pragma unroll
        for (int cc = 1; cc < 16; ++cc) m = fmaxf(m, sm[cc][d]);
        shg[d] = (m - gmu[d]) * gmu[64];
    }
    __syncthreads();
    if (t < DD) {
        float acc = b1[t];
        for (int k = 0; k < DD; ++k) acc = fmaf(shg[k], W1[k * DD + t], acc);
        st[t] = fmaxf(acc, 0.f);
    }
    __syncthreads();
    if (t < 2) {
        float o = b2[t];
        for (int k = 0; k < DD; ++k) o = fmaf(st[k], W2[k * 2 + t], o);
        out[g * 2 + t] = o;
    }
}

// ---------------------------------------------------------------- launch
extern "C" void kernel_launch(void* const* d_in, const int* in_sizes, int n_in,
                              void* d_out, int out_size, void* d_ws, size_t ws_size,
                              hipStream_t stream) {
    (void)in_sizes; (void)n_in; (void)out_size; (void)ws_size;
    const float* h_in = (const float*)d_in[0];
    const float* pos  = (const float*)d_in[1];
    const int*   eidx = (const int*)d_in[2];
    const float* Wemb = (const float*)d_in[4];
    const float* bemb = (const float*)d_in[5];
    const float* msgW = (const float*)d_in[6]; // 2 x 129 x 64
    const float* msgb = (const float*)d_in[7]; // 2 x 64
    const float* updW = (const float*)d_in[8]; // 2 x 128 x 64
    const float* updb = (const float*)d_in[9]; // 2 x 64
    const float* W1   = (const float*)d_in[10];
    const float* b1   = (const float*)d_in[11];
    const float* W2   = (const float*)d_in[12];
    const float* b2   = (const float*)d_in[13];
    float* out = (float*)d_out;

    float* hbuf  = (float*)d_ws;                 // N*64 fp32 (layer-1 C / final hraw)
    float* Cbuf  = hbuf + NN * DD;               // N*64 fp32 (layer-0 C / hraw0)
    float* aggr  = Cbuf + NN * DD;               // N*64 fp32
    unsigned short* A16 = (unsigned short*)(aggr + NN * DD);  // N*64 bf16
    unsigned short* B16 = A16 + NN * DD;         // N*64 bf16
    float* gmu0  = (float*)(B16 + NN * DD);      // 66
    float* gmu1  = gmu0 + 66;                    // 66
    float* part2 = gmu1 + 66;                    // 64*68
    float* part  = part2 + S1_BLOCKS * 68;       // AB2_BLOCKS*68
    int* counts  = (int*)(part + AB2_BLOCKS * 68);// N (zeroed)
    int* counter = counts + NN;                  // 1 (zeroed)
    int2* ep     = (int2*)(counts + NN + 4);     // N*CAP slots

    const int* src = eidx;
    const int* dst = eidx + EE;

    hipMemsetAsync(counts, 0, (NN + 4) * sizeof(int), stream);

    // ---- layer 0 (embed + scatter + ABC in one dispatch)
    k_ab0<<<AB2_BLOCKS + SCAT2_BLOCKS, 512, 0, stream>>>(
        h_in, Wemb, bemb, msgW, msgb, updW, updb,
        src, dst, pos, counts, ep, A16, B16, Cbuf);
    k_edge<<<(NN + 3) / 4, 256, 0, stream>>>(A16, B16, msgW + 128 * DD,
                                             counts, ep, aggr);
    k_upd<<<AB2_BLOCKS, 512, 0, stream>>>(aggr, Cbuf, updW + 64 * DD, Cbuf, part);
    k_stats<<<S1_BLOCKS, 128, 0, stream>>>(part, part2, gmu0, counter);

    // ---- layer 1
    {
        const float* Wm = msgW + 129 * DD;
        k_ab1<<<AB2_BLOCKS, 512, 0, stream>>>(Cbuf, gmu0, Wm, msgb + DD,
                                              updW + 128 * DD, updb + DD,
                                              A16, B16, hbuf);
        k_edge<<<(NN + 3) / 4, 256, 0, stream>>>(A16, B16, Wm + 128 * DD,
                                                 counts, ep, aggr);
        k_upd<<<AB2_BLOCKS, 512, 0, stream>>>(aggr, hbuf, updW + 192 * DD, hbuf, part);
        k_stats<<<S1_BLOCKS, 128, 0, stream>>>(part, part2, gmu1, counter);
    }

    k_poolhead<<<GG, 1024, 0, stream>>>(hbuf, gmu1, W1, b1, W2, b2, out);
}